// Round 29
// baseline (209.926 us; speedup 1.0000x reference)
//
#include <hip/hip_runtime.h>
#include <math.h>

#define B_ 4
#define N_ 1024
#define C_ 1024
#define H_ 16
#define D_ 64
#define P_ 5
#define BN_ (B_*N_)
#define TOK 8

typedef unsigned int u32;
typedef unsigned short u16;
typedef __attribute__((ext_vector_type(8))) short bf16x8;
typedef __attribute__((ext_vector_type(4))) float f32x4;

__device__ __forceinline__ float gelu_f(float x){
  float x3 = x*x*x;
  return 0.5f*x*(1.0f + tanhf(0.7978845608028654f*(x + 0.044715f*x3)));
}
__device__ __forceinline__ float sigmoid_f(float x){ return 1.0f/(1.0f+expf(-x)); }

__device__ __forceinline__ u16 f2bf(float f) {
  u32 u = __float_as_uint(f);
  u32 r = u + 0x7fffu + ((u >> 16) & 1u);
  return (u16)(r >> 16);
}
__device__ __forceinline__ float bf2f(u16 v){ return __uint_as_float(((u32)v) << 16); }

__device__ __forceinline__ void gload16(const void* g, void* l) {
  __builtin_amdgcn_global_load_lds((const __attribute__((address_space(1))) u32*)g,
                                   (__attribute__((address_space(3))) u32*)l, 16, 0, 0);
}

// ---- transpose block: fp32 W[K][Nn] tile (r0,c0) -> bf16 Wt[roff+c][K] -------
__device__ __forceinline__ void trans_block(const float* __restrict__ W,
    u16* __restrict__ Wt, int K, int Nn, int roff, int bxx, int byy,
    float (*t)[33], int tid) {
  const int c0 = bxx * 32, r0 = byy * 32;
  const int tx = tid & 31, ty = tid >> 5;
  #pragma unroll
  for (int i = 0; i < 4; ++i) {
    int r = ty + i * 8;
    t[r][tx] = (c0 + tx < Nn) ? W[(size_t)(r0 + r) * Nn + c0 + tx] : 0.f;
  }
  __syncthreads();
  #pragma unroll
  for (int i = 0; i < 4; ++i) {
    int r = ty + i * 8;
    if (c0 + r < Nn)
      Wt[(size_t)(roff + c0 + r) * K + r0 + tx] = f2bf(t[tx][r]);
  }
}

// ---- fused setup: x cast + all weight transposes into wcat + pads + biases ---
__global__ __launch_bounds__(256) void setup_k(const float* __restrict__ x,
    const float* __restrict__ W_qkv, const float* __restrict__ W_id,
    const float* __restrict__ W_g1, const float* __restrict__ W_proj,
    const float* __restrict__ W_gate, const float* __restrict__ W_prune,
    const float* __restrict__ W_g2, const float* __restrict__ bg,
    const float* __restrict__ bp, const float* __restrict__ bg2,
    u16* __restrict__ xb, u16* __restrict__ wcat, u16* __restrict__ wprojT,
    u16* __restrict__ catG2, float* __restrict__ cb1, float* __restrict__ cb2,
    float* __restrict__ entA) {
  __shared__ float t[32][33];
  int bid = blockIdx.x;
  const int tid = threadIdx.x;
  if (bid < 2048) {
    int i = bid * 256 + tid;
    const float4* p = (const float4*)x + (size_t)i * 2;
    float4 a = p[0], b = p[1];
    uint4 o;
    o.x = (u32)f2bf(a.x) | ((u32)f2bf(a.y) << 16);
    o.y = (u32)f2bf(a.z) | ((u32)f2bf(a.w) << 16);
    o.z = (u32)f2bf(b.x) | ((u32)f2bf(b.y) << 16);
    o.w = (u32)f2bf(b.z) | ((u32)f2bf(b.w) << 16);
    *(uint4*)(xb + (size_t)i * 8) = o;
    return;
  }
  bid -= 2048;
  if (bid < 3072) { trans_block(W_qkv, wcat, 1024, 3072, 0, bid % 96, bid / 96, t, tid); return; }
  bid -= 3072;
  if (bid < 1024) { trans_block(W_id, wcat, 1024, 1024, 3072, bid & 31, bid >> 5, t, tid); return; }
  bid -= 1024;
  if (bid < 1024) { trans_block(W_g1, wcat, 1024, 1024, 4096, bid & 31, bid >> 5, t, tid); return; }
  bid -= 1024;
  if (bid < 1024) { trans_block(W_proj, wprojT, 1024, 1024, 0, bid & 31, bid >> 5, t, tid); return; }
  bid -= 1024;
  if (bid < 32)  { trans_block(W_gate, wcat, 1024, 16, 5120, 0, bid, t, tid); return; }
  bid -= 32;
  if (bid < 96)  { trans_block(W_prune, wcat, 1024, 80, 5136, bid % 3, bid / 3, t, tid); return; }
  bid -= 96;
  if (bid < 96)  { trans_block(W_g2, catG2, 1024, 80, 0, bid % 3, bid / 3, t, tid); return; }
  bid -= 96;
  if (bid < 8) {
    int idx = (bid * 256 + tid) * 16;
    *(uint4*)(wcat + (size_t)5216 * 1024 + idx) = make_uint4(0, 0, 0, 0);
    *(uint4*)(wcat + (size_t)5216 * 1024 + idx + 8) = make_uint4(0, 0, 0, 0);
    return;
  }
  bid -= 8;
  if (bid < 12) {
    int idx = (bid * 256 + tid) * 16;
    *(uint4*)(catG2 + 80 * 1024 + idx) = make_uint4(0, 0, 0, 0);
    *(uint4*)(catG2 + 80 * 1024 + idx + 8) = make_uint4(0, 0, 0, 0);
    return;
  }
  if (tid < 128) cb1[tid] = (tid < 16) ? bg[tid] : (tid < 96 ? bp[tid - 16] : 0.f);
  else { int c = tid - 128; cb2[c] = (c < 80) ? bg2[c] : 0.f; }
  if (tid == 0) entA[0] = 0.f;
}

// ---- merged qkvi+g1+gate/prune GEMM: xb @ wcat (N=5248), routed epilogue -----
// 1D grid 656 = 8 XCD x 82, XCD-bijective remap: half = slot&1, bx = slot>>1
// so the TWO blocks sharing a B col-panel (halves of the same bx) are adjacent
// in dispatch -> co-resident -> one L2 fill of the B panel serves both.
// A row panels (2 per XCD, 1 MB) stay L2-resident. 3-buffer counted vmcnt
// (R27 lesson: do NOT reduce pipeline depth / raise blocks-per-CU).
__global__ __launch_bounds__(512, 4) void gemm_qg(const u16* __restrict__ A,
    const u16* __restrict__ Bt, const float* __restrict__ b_g1,
    const float* __restrict__ cb1, u16* __restrict__ qkviOut,
    u16* __restrict__ hb16, float* __restrict__ gp) {
  __shared__ __align__(16) u16 lA[3][256 * 32];
  __shared__ __align__(16) u16 lB[3][128 * 32];
  const int tid = threadIdx.x;
  const int lane = tid & 63, wid = tid >> 6;      // 0..7
  const int wr = wid >> 1, wc = wid & 1;
  const int r16 = lane & 15, kq = lane >> 4;
  const int ib = blockIdx.x;
  const int xcd = ib & 7, slot = ib >> 3;          // 82 slots per XCD
  const int half = slot & 1;
  const int bx = slot >> 1;                        // 0..40
  const int by = xcd * 2 + half;
  const int row0 = by * 256, col0 = bx * 128;
  const int srow = lane >> 2;
  const int skoff = (((lane & 3) ^ ((srow >> 1) & 3)) << 3);
  const int rsw = ((r16 >> 1) & 3);
  const int K = 1024, T = 32;

  #define STAGE2(buf, tk) { \
    const int k0_ = (tk) << 5; \
    _Pragma("unroll") \
    for (int s = 0; s < 2; ++s) { \
      int c = wid * 2 + s; \
      int rt = c * 16 + srow; \
      gload16(A + (size_t)(row0 + rt) * K + k0_ + skoff, &lA[buf][c * 512]); \
    } \
    { \
      int rtB = wid * 16 + srow; \
      gload16(Bt + (size_t)(col0 + rtB) * K + k0_ + skoff, &lB[buf][wid * 512]); \
    } }

  f32x4 acc[4][4] = {};
  STAGE2(0, 0);
  STAGE2(1, 1);

  for (int t = 0; t < T; ++t) {
    if (t < T - 1) asm volatile("s_waitcnt vmcnt(3)" ::: "memory");
    else           asm volatile("s_waitcnt vmcnt(0)" ::: "memory");
    __builtin_amdgcn_s_barrier();
    asm volatile("" ::: "memory");
    if (t + 2 < T) { const int bnx = (t + 2) % 3; STAGE2(bnx, t + 2); }
    const int bc = t % 3;
    const int ko = ((kq ^ rsw) << 3);
    bf16x8 af[4], bfv[4];
    #pragma unroll
    for (int m = 0; m < 4; ++m)
      af[m] = *(const bf16x8*)&lA[bc][(wr * 64 + m * 16 + r16) * 32 + ko];
    #pragma unroll
    for (int n = 0; n < 4; ++n)
      bfv[n] = *(const bf16x8*)&lB[bc][(wc * 64 + n * 16 + r16) * 32 + ko];
    #pragma unroll
    for (int m = 0; m < 4; ++m)
      #pragma unroll
      for (int n = 0; n < 4; ++n)
        acc[m][n] = __builtin_amdgcn_mfma_f32_16x16x32_bf16(af[m], bfv[n], acc[m][n], 0, 0, 0);
  }
  #undef STAGE2

  if (col0 < 4096) {
    // ---- qkvi region: q/k l2norm + bf16 store ----
    const int hb = (col0 + wc * 64) >> 6;
    if (hb < 32) {
      float sc[4][4];
      #pragma unroll
      for (int m = 0; m < 4; ++m)
        #pragma unroll
        for (int r = 0; r < 4; ++r) {
          float s = 0.f;
          #pragma unroll
          for (int n = 0; n < 4; ++n) s = fmaf(acc[m][n][r], acc[m][n][r], s);
          s += __shfl_xor(s, 1); s += __shfl_xor(s, 2);
          s += __shfl_xor(s, 4); s += __shfl_xor(s, 8);
          float tsc = rsqrtf(s + 1e-6f);
          sc[m][r] = (hb < 16) ? tsc * 0.125f : tsc;
        }
      #pragma unroll
      for (int m = 0; m < 4; ++m)
        #pragma unroll
        for (int n = 0; n < 4; ++n)
          #pragma unroll
          for (int r = 0; r < 4; ++r) acc[m][n][r] *= sc[m][r];
    }
    #pragma unroll
    for (int n = 0; n < 4; ++n) {
      int col = col0 + wc * 64 + n * 16 + r16;
      #pragma unroll
      for (int m = 0; m < 4; ++m) {
        int rowb = row0 + wr * 64 + m * 16 + kq * 4;
        #pragma unroll
        for (int r = 0; r < 4; ++r)
          qkviOut[(size_t)(rowb + r) * 4096 + col] = f2bf(acc[m][n][r]);
      }
    }
  } else {
    // ---- g1 / gate+prune region ----
    #pragma unroll
    for (int n = 0; n < 4; ++n) {
      const int col = col0 + wc * 64 + n * 16 + r16;
      if (col < 5120) {
        const int c1 = col - 4096;
        const float bs = b_g1[c1];
        #pragma unroll
        for (int m = 0; m < 4; ++m) {
          int rowb = row0 + wr * 64 + m * 16 + kq * 4;
          #pragma unroll
          for (int r = 0; r < 4; ++r)
            hb16[(size_t)(rowb + r) * 1024 + c1] = f2bf(gelu_f(acc[m][n][r] + bs));
        }
      } else if (col < 5216) {
        const int c2 = col - 5120;
        const float bs = cb1[c2];
        #pragma unroll
        for (int m = 0; m < 4; ++m) {
          int rowb = row0 + wr * 64 + m * 16 + kq * 4;
          #pragma unroll
          for (int r = 0; r < 4; ++r)
            gp[(size_t)(rowb + r) * 96 + c2] = acc[m][n][r] + bs;
        }
      }
    }
  }
}

// ------ bf16 MFMA GEMM 128^2, 3-buffer pipelined + swizzle (g2l, proj) --------
template<int ACT, int OBF, int ENT>
__global__ __launch_bounds__(256) void gemm_mfma(const u16* __restrict__ A,
    const u16* __restrict__ Bt, const float* __restrict__ bias,
    float* __restrict__ Cout, int M, int Nn, int K, int Ns,
    const float* __restrict__ entSrc, float* __restrict__ entDst) {
  __shared__ __align__(16) u16 lA[3][128 * 32];
  __shared__ __align__(16) u16 lB[3][128 * 32];
  const int tid = threadIdx.x;
  const int lane = tid & 63, wid = tid >> 6;
  const int wr = wid >> 1, wc = wid & 1;
  const int r16 = lane & 15, kq = lane >> 4;
  const int row0 = blockIdx.y * 128, col0 = blockIdx.x * 128;
  const int c0 = wid * 2;
  const int srow = lane >> 2;
  const int skoff = (((lane & 3) ^ ((srow >> 1) & 3)) << 3);
  const int rsw = ((r16 >> 1) & 3);
  const int T = K >> 5;

  if (ENT && blockIdx.x == 0 && blockIdx.y == 0 && tid == 0)
    entDst[0] = entSrc[0] * (1.0f / 65536.0f);

  #define STAGE_T(buf, tk) { \
    const int k0_ = (tk) << 5; \
    _Pragma("unroll") \
    for (int s = 0; s < 2; ++s) { \
      int c = c0 + s; \
      int rt = c * 16 + srow; \
      gload16(A  + (size_t)(row0 + rt) * K + k0_ + skoff, &lA[buf][c * 512]); \
      gload16(Bt + (size_t)(col0 + rt) * K + k0_ + skoff, &lB[buf][c * 512]); \
    } }

  f32x4 acc[4][4] = {};
  STAGE_T(0, 0);
  if (T > 1) STAGE_T(1, 1);

  for (int t = 0; t < T; ++t) {
    if (t < T - 1) asm volatile("s_waitcnt vmcnt(4)" ::: "memory");
    else           asm volatile("s_waitcnt vmcnt(0)" ::: "memory");
    __builtin_amdgcn_s_barrier();
    asm volatile("" ::: "memory");
    if (t + 2 < T) { const int bnx = (t + 2) % 3; STAGE_T(bnx, t + 2); }
    const int bc = t % 3;
    const int ko = ((kq ^ rsw) << 3);
    bf16x8 af[4], bfv[4];
    #pragma unroll
    for (int m = 0; m < 4; ++m)
      af[m] = *(const bf16x8*)&lA[bc][(wr * 64 + m * 16 + r16) * 32 + ko];
    #pragma unroll
    for (int n = 0; n < 4; ++n)
      bfv[n] = *(const bf16x8*)&lB[bc][(wc * 64 + n * 16 + r16) * 32 + ko];
    #pragma unroll
    for (int m = 0; m < 4; ++m)
      #pragma unroll
      for (int n = 0; n < 4; ++n)
        acc[m][n] = __builtin_amdgcn_mfma_f32_16x16x32_bf16(af[m], bfv[n], acc[m][n], 0, 0, 0);
  }
  #undef STAGE_T

  #pragma unroll
  for (int n = 0; n < 4; ++n) {
    int col = col0 + wc * 64 + n * 16 + r16;
    if (col >= Ns) continue;
    float bs = bias ? bias[col] : 0.0f;
    #pragma unroll
    for (int m = 0; m < 4; ++m) {
      int rowb = row0 + wr * 64 + m * 16 + kq * 4;
      #pragma unroll
      for (int r = 0; r < 4; ++r) {
        float v = acc[m][n][r] + bs;
        if (ACT == 1) v = gelu_f(v);
        if (OBF) ((u16*)Cout)[(size_t)(rowb + r) * Ns + col] = f2bf(v);
        else     Cout[(size_t)(rowb + r) * Ns + col] = v;
      }
    }
  }
}

// ------- DeltaNet prep: M via MFMA from normalized k̂ (qkvi), T' solve --------
__global__ __launch_bounds__(256) void delta_prep(const u16* __restrict__ qkvi,
    u16* __restrict__ tb) {
  const int bx = blockIdx.x;
  const int bh = bx >> 4, g = bx & 15;
  const int b = bh >> 4, h = bh & 15;
  const int n0 = g * 64;
  const int tid = threadIdx.x;
  __shared__ __align__(16) u16 sKb[64][72];
  __shared__ __align__(16) float sMT[64][68];
  __shared__ float sBeta[64];

  if (tid < 64) sBeta[tid] = 1.0f - 0.9f * (float)(n0 + tid) / 1023.0f;

  const int fr = tid >> 2, fe0 = (tid & 3) * 16;
  const size_t krow = ((size_t)b * N_ + n0 + fr) * 4096 + 1024 + h * 64 + fe0;
  *(uint4*)&sKb[fr][fe0]     = *(const uint4*)(qkvi + krow);
  *(uint4*)&sKb[fr][fe0 + 8] = *(const uint4*)(qkvi + krow + 8);
  __syncthreads();

  {
    const int lane = tid & 63, wv = tid >> 6;
    const int l15 = lane & 15, l4 = lane >> 4;
    bf16x8 ka0 = *(const bf16x8*)&sKb[16*wv + l15][l4*8];
    bf16x8 ka1 = *(const bf16x8*)&sKb[16*wv + l15][32 + l4*8];
    #pragma unroll
    for (int ct = 0; ct < 4; ++ct) {
      bf16x8 kc0 = *(const bf16x8*)&sKb[ct*16 + l15][l4*8];
      bf16x8 kc1 = *(const bf16x8*)&sKb[ct*16 + l15][32 + l4*8];
      f32x4 m = {};
      m = __builtin_amdgcn_mfma_f32_16x16x32_bf16(ka0, kc0, m, 0, 0, 0);
      m = __builtin_amdgcn_mfma_f32_16x16x32_bf16(ka1, kc1, m, 0, 0, 0);
      const int c = ct*16 + l15, rbase = 16*wv + l4*4;
      float4 o;
      o.x = (rbase+0 > c) ? sBeta[rbase+0] * m[0] : 0.f;
      o.y = (rbase+1 > c) ? sBeta[rbase+1] * m[1] : 0.f;
      o.z = (rbase+2 > c) ? sBeta[rbase+2] * m[2] : 0.f;
      o.w = (rbase+3 > c) ? sBeta[rbase+3] * m[3] : 0.f;
      *(float4*)&sMT[c][rbase] = o;
    }
  }
  __syncthreads();

  if (tid < 64) {
    const int c = tid;
    float a[64];
    #pragma unroll
    for (int i = 0; i < 64; ++i) a[i] = (i == c) ? 1.f : 0.f;
    #pragma unroll
    for (int ib = 0; ib < 4; ++ib) {
      #pragma unroll
      for (int i2 = 0; i2 < 16; ++i2) {
        const int i = ib * 16 + i2;
        const float wi = a[i];
        #pragma unroll
        for (int j4 = ib * 4; j4 < 16; ++j4) {
          const float4 m = *(const float4*)&sMT[i][j4 * 4];
          a[j4*4+0] = fmaf(-m.x, wi, a[j4*4+0]);
          a[j4*4+1] = fmaf(-m.y, wi, a[j4*4+1]);
          a[j4*4+2] = fmaf(-m.z, wi, a[j4*4+2]);
          a[j4*4+3] = fmaf(-m.w, wi, a[j4*4+3]);
        }
      }
    }
    const float bc = sBeta[c];
    const size_t obase = (size_t)bx * 4096;
    #pragma unroll
    for (int i = 0; i < 64; ++i) tb[obase + i * 64 + c] = f2bf(a[i] * bc);
  }
}

// -------- DeltaNet fused scan+output, dv-split x4, XCD-co-located quarters ----
__global__ __launch_bounds__(256, 1) void delta_fused(const u16* __restrict__ tb,
    const u16* __restrict__ qkvi, u16* __restrict__ dOutb) {
  const int bh = blockIdx.x & 63, q4 = blockIdx.x >> 6;
  const int b = bh >> 4, h = bh & 15;
  const int dvo = q4 * 16;
  const int tid = threadIdx.x;
  const int lane = tid & 63, wv = tid >> 6;
  const int l15 = lane & 15, l4 = lane >> 4;
  const int fr = tid >> 2, fe0 = (tid & 3) * 16;
  const int fe2 = (tid & 3) * 4;

  __shared__ __align__(16) u16 sK [64][72];
  __shared__ __align__(16) u16 sKT[64][72];
  __shared__ __align__(16) u16 sT [64][72];
  __shared__ __align__(16) u16 sQ [64][72];
  __shared__ __align__(16) u16 sV [64][24];
  __shared__ __align__(16) u16 sSt[16][72];
  __shared__ __align__(16) u16 sYt[16][72];
  __shared__ __align__(16) u16 sUt[16][72];
  __shared__ __align__(16) u16 sA [64][72];

  f32x4 Sacc = {};

  uint4 pk0, pk1, pt0, pt1, pq0, pq1;
  uint2 pv0;
  {
    const size_t bs = (size_t)(bh * 16) * 4096;
    const size_t rowq = ((size_t)(b * 1024 + fr)) * 4096 + h * 64 + fe0;
    const size_t rowv = ((size_t)(b * 1024 + fr)) * 4096 + 2048 + h * 64 + dvo + fe2;
    pq0 = *(const uint4*)(qkvi + rowq);        pq1 = *(const uint4*)(qkvi + rowq + 8);
    pk0 = *(const uint4*)(qkvi + rowq + 1024); pk1 = *(const uint4*)(qkvi + rowq + 1024 + 8);
    pv0 = *(const uint2*)(qkvi + rowv);
    pt0 = *(const uint4*)(tb + bs + tid*16);   pt1 = *(const uint4*)(tb + bs + tid*16 + 8);
  }

  for (int g = 0; g < 16; ++g) {
    __syncthreads();
    *(uint4*)&sK[fr][fe0] = pk0; *(uint4*)&sK[fr][fe0+8] = pk1;
    *(uint4*)&sT[fr][fe0] = pt0; *(uint4*)&sT[fr][fe0+8] = pt1;
    *(uint4*)&sQ[fr][fe0] = pq0; *(uint4*)&sQ[fr][fe0+8] = pq1;
    *(uint2*)&sV[fr][fe2] = pv0;
    {
      u32 kk[8] = {pk0.x, pk0.y, pk0.z, pk0.w, pk1.x, pk1.y, pk1.z, pk1.w};
      #pragma unroll
      for (int i = 0; i < 8; ++i) {
        sKT[fe0 + 2*i][fr]     = (u16)kk[i];
        sKT[fe0 + 2*i + 1][fr] = (u16)(kk[i] >> 16);
      }
    }
    {
      u32 lo = (u32)f2bf(Sacc[0]) | ((u32)f2bf(Sacc[1]) << 16);
      u32 hi = (u32)f2bf(Sacc[2]) | ((u32)f2bf(Sacc[3]) << 16);
      *(u32*)&sSt[l15][16*wv + l4*4]     = lo;
      *(u32*)&sSt[l15][16*wv + l4*4 + 2] = hi;
    }
    __syncthreads();
    if (g < 15) {
      const size_t bs = (size_t)(bh * 16 + g + 1) * 4096;
      const size_t rowq = ((size_t)(b * 1024 + (g + 1) * 64 + fr)) * 4096 + h * 64 + fe0;
      const size_t rowv = ((size_t)(b * 1024 + (g + 1) * 64 + fr)) * 4096 + 2048 + h * 64 + dvo + fe2;
      pq0 = *(const uint4*)(qkvi + rowq);        pq1 = *(const uint4*)(qkvi + rowq + 8);
      pk0 = *(const uint4*)(qkvi + rowq + 1024); pk1 = *(const uint4*)(qkvi + rowq + 1024 + 8);
      pv0 = *(const uint2*)(qkvi + rowv);
      pt0 = *(const uint4*)(tb + bs + tid*16);   pt1 = *(const uint4*)(tb + bs + tid*16 + 8);
    }
    bf16x8 qf0 = *(const bf16x8*)&sQ[16*wv + l15][l4*8];
    bf16x8 qf1 = *(const bf16x8*)&sQ[16*wv + l15][32 + l4*8];
    bf16x8 kr0 = *(const bf16x8*)&sK[16*wv + l15][l4*8];
    bf16x8 kr1 = *(const bf16x8*)&sK[16*wv + l15][32 + l4*8];
    f32x4 aacc[4] = {}, yacc = {}, oacc = {};
    #pragma unroll
    for (int ct = 0; ct < 4; ++ct) {
      bf16x8 kc0 = *(const bf16x8*)&sK[ct*16 + l15][l4*8];
      bf16x8 kc1 = *(const bf16x8*)&sK[ct*16 + l15][32 + l4*8];
      aacc[ct] = __builtin_amdgcn_mfma_f32_16x16x32_bf16(qf0, kc0, aacc[ct], 0, 0, 0);
      aacc[ct] = __builtin_amdgcn_mfma_f32_16x16x32_bf16(qf1, kc1, aacc[ct], 0, 0, 0);
    }
    {
      bf16x8 s0 = *(const bf16x8*)&sSt[l15][l4*8];
      bf16x8 s1 = *(const bf16x8*)&sSt[l15][32 + l4*8];
      yacc = __builtin_amdgcn_mfma_f32_16x16x32_bf16(kr0, s0, yacc, 0, 0, 0);
      yacc = __builtin_amdgcn_mfma_f32_16x16x32_bf16(kr1, s1, yacc, 0, 0, 0);
      oacc = __builtin_amdgcn_mfma_f32_16x16x32_bf16(qf0, s0, oacc, 0, 0, 0);
      oacc = __builtin_amdgcn_mfma_f32_16x16x32_bf16(qf1, s1, oacc, 0, 0, 0);
    }
    {
      float y0 = bf2f(sV[16*wv + l4*4 + 0][l15]) - yacc[0];
      float y1 = bf2f(sV[16*wv + l4*4 + 1][l15]) - yacc[1];
      float y2 = bf2f(sV[16*wv + l4*4 + 2][l15]) - yacc[2];
      float y3 = bf2f(sV[16*wv + l4*4 + 3][l15]) - yacc[3];
      u32 lo = (u32)f2bf(y0) | ((u32)f2bf(y1) << 16);
      u32 hi = (u32)f2bf(y2) | ((u32)f2bf(y3) << 16);
      *(u32*)&sYt[l15][16*wv + l4*4]     = lo;
      *(u32*)&sYt[l15][16*wv + l4*4 + 2] = hi;
    }
    #pragma unroll
    for (int ct = 0; ct < 4; ++ct)
      #pragma unroll
      for (int j = 0; j < 4; ++j) {
        int r = 16*wv + l4*4 + j, c = ct*16 + l15;
        sA[r][c] = f2bf((r >= c) ? aacc[ct][j] : 0.f);
      }
    __syncthreads();
    bf16x8 tf0 = *(const bf16x8*)&sT[16*wv + l15][l4*8];
    bf16x8 tf1 = *(const bf16x8*)&sT[16*wv + l15][32 + l4*8];
    f32x4 uacc = {};
    {
      bf16x8 y0 = *(const bf16x8*)&sYt[l15][l4*8];
      bf16x8 y1 = *(const bf16x8*)&sYt[l15][32 + l4*8];
      uacc = __builtin_amdgcn_mfma_f32_16x16x32_bf16(tf0, y0, uacc, 0, 0, 0);
      uacc = __builtin_amdgcn_mfma_f32_16x16x32_bf16(tf1, y1, uacc, 0, 0, 0);
    }
    {
      u32 lo = (u32)f2bf(uacc[0]) | ((u32)f2bf(uacc[1]) << 16);
      u32 hi = (u32)f2bf(uacc[2]) | ((u32)f2bf(uacc[3]) << 16);
      *(u32*)&sUt[l15][16*wv + l4*4]     = lo;
      *(u32*)&sUt[l15][16*wv + l4*4 + 2] = hi;
    }
    __syncthreads();
    bf16x8 af0 = *(const bf16x8*)&sA[16*wv + l15][l4*8];
    bf16x8 af1 = *(const bf16x8*)&sA[16*wv + l15][32 + l4*8];
    bf16x8 kt0 = *(const bf16x8*)&sKT[16*wv + l15][l4*8];
    bf16x8 kt1 = *(const bf16x8*)&sKT[16*wv + l15][32 + l4*8];
    {
      bf16x8 u0 = *(const bf16x8*)&sUt[l15][l4*8];
      bf16x8 u1 = *(const bf16x8*)&sUt[l15][32 + l4*8];
      oacc = __builtin_amdgcn_mfma_f32_16x16x32_bf16(af0, u0, oacc, 0, 0, 0);
      oacc = __builtin_amdgcn_mfma_f32_16x16x32_bf16(af1, u1, oacc, 0, 0, 0);
      Sacc = __builtin_amdgcn_mfma_f32_16x16x32_bf16(kt0, u0, Sacc, 0, 0, 0);
      Sacc = __builtin_amdgcn_mfma_f32_16x16x32_bf16(kt1, u1, Sacc, 0, 0, 0);
    }
    #pragma unroll
    for (int j = 0; j < 4; ++j) {
      int r = 16*wv + l4*4 + j;
      dOutb[((size_t)(b * 1024 + g * 64 + r)) * 1024 + h * 64 + dvo + l15] = f2bf(oacc[j]);
    }
  }
}

// ------- fused FIR + mix + gating + ctx; contiguous 4-elem ownership ----------
__global__ __launch_bounds__(256) void paths2(const u16* __restrict__ qkvi,
    const u16* __restrict__ dOutb, const float* __restrict__ gp,
    const float* __restrict__ g2L, const float* __restrict__ fir_s,
    const float* __restrict__ fir_l, const float* __restrict__ mix,
    const float* __restrict__ idlog, u16* __restrict__ ctxb,
    float* __restrict__ entAcc) {
  const int bid = ((blockIdx.x & 7) << 6) | (blockIdx.x >> 3);
  const int b = bid >> 7, n0 = (bid & 127) * TOK;
  const int tid = threadIdx.x;
  __shared__ u16 sV[TOK + 6][1024];
  __shared__ u32 sFSL[TOK][1024];           // packed: fs | fl<<16
  __shared__ float sMix[256];
  __shared__ float sWg[TOK][16][5];
  __shared__ float sIdg[TOK][16];
  __shared__ float sEnt[128];
  sMix[tid] = mix[tid];

  #pragma unroll
  for (int i = 0; i < 7; ++i) {
    int r = i * 2 + (tid >> 7);
    int t = n0 - 6 + r;
    int col = (tid & 127) * 8;
    uint4 v = make_uint4(0, 0, 0, 0);
    if (t >= 0)
      v = *(const uint4*)(qkvi + ((size_t)b * 1024 + t) * 4096 + 2048 + col);
    *(uint4*)&sV[r][col] = v;
  }

  if (tid < 128) {
    const int tok = tid >> 4, hh = tid & 15;
    const size_t bn = (size_t)b * 1024 + n0 + tok;
    float pl[5], lp[5];
    #pragma unroll
    for (int p = 0; p < 5; ++p) pl[p] = gp[bn * 96 + 16 + hh * 5 + p];
    float mx = pl[0];
    #pragma unroll
    for (int p = 1; p < 5; ++p) mx = fmaxf(mx, pl[p]);
    float s = 0.f;
    #pragma unroll
    for (int p = 0; p < 5; ++p) { pl[p] = expf(pl[p] - mx); s += pl[p]; }
    float inv = 1.f / s, e1 = 0.f;
    #pragma unroll
    for (int p = 0; p < 5; ++p) {
      float prob = pl[p] * inv;
      lp[p] = logf(prob + 1e-8f);
      e1 -= prob * lp[p];
    }
    float gl[5];
    #pragma unroll
    for (int p = 0; p < 5; ++p) gl[p] = g2L[bn * 80 + hh * 5 + p] + lp[p];
    float mx2 = gl[0];
    #pragma unroll
    for (int p = 1; p < 5; ++p) mx2 = fmaxf(mx2, gl[p]);
    float s2 = 0.f;
    #pragma unroll
    for (int p = 0; p < 5; ++p) { gl[p] = expf(gl[p] - mx2); s2 += gl[p]; }
    float inv2 = 1.f / s2, e2 = 0.f;
    #pragma unroll
    for (int p = 0; p < 5; ++p) {
      float w = gl[p] * inv2;
      sWg[tok][hh][p] = w;
      e2 -= w * logf(w + 1e-8f);
    }
    sEnt[tid] = e1 + e2;
    sIdg[tok][hh] = sigmoid_f(gp[bn * 96 + hh]) * sigmoid_f(idlog[hh]);
  }
  __syncthreads();

  const int idx0 = tid * 4;                // 4 consecutive elems, same head
  const int gg = idx0 >> 6, d0 = idx0 & 63;

  // FIR: b64 tap reads, b128 packed write
  {
    float fl7[4][7], fs3[4][3];
    #pragma unroll
    for (int e = 0; e < 4; ++e) {
      #pragma unroll
      for (int j = 0; j < 7; ++j) fl7[e][j] = fir_l[(size_t)(idx0 + e) * 7 + j];
      #pragma unroll
      for (int j = 0; j < 3; ++j) fs3[e][j] = fir_s[(size_t)(idx0 + e) * 3 + j];
    }
    #pragma unroll
    for (int tok = 0; tok < TOK; ++tok) {
      float accs[4] = {}, accl[4] = {};
      #pragma unroll
      for (int j = 0; j < 7; ++j) {
        uint2 v2 = *(const uint2*)&sV[tok + j][idx0];
        float vv[4] = { bf2f((u16)v2.x), bf2f((u16)(v2.x >> 16)),
                        bf2f((u16)v2.y), bf2f((u16)(v2.y >> 16)) };
        #pragma unroll
        for (int e = 0; e < 4; ++e) {
          accl[e] = fmaf(fl7[e][j], vv[e], accl[e]);
          if (j >= 4) accs[e] = fmaf(fs3[e][j - 4], vv[e], accs[e]);
        }
      }
      uint4 pk;
      pk.x = (u32)f2bf(accs[0]) | ((u32)f2bf(accl[0]) << 16);
      pk.y = (u32)f2bf(accs[1]) | ((u32)f2bf(accl[1]) << 16);
      pk.z = (u32)f2bf(accs[2]) | ((u32)f2bf(accl[2]) << 16);
      pk.w = (u32)f2bf(accs[3]) | ((u32)f2bf(accl[3]) << 16);
      *(uint4*)&sFSL[tok][idx0] = pk;
    }
  }
  __syncthreads();

  // mix + combine: b128 gathers, b64 global IO
  #pragma unroll
  for (int tok = 0; tok < TOK; ++tok) {
    const size_t bn = (size_t)b * 1024 + n0 + tok;
    uint4 own = *(const uint4*)&sFSL[tok][idx0];
    u32 ow[4] = {own.x, own.y, own.z, own.w};
    float as[4], al[4];
    #pragma unroll
    for (int e = 0; e < 4; ++e) { as[e] = bf2f((u16)ow[e]); al[e] = bf2f((u16)(ow[e] >> 16)); }
    #pragma unroll
    for (int hh = 0; hh < 16; ++hh) {
      float m = sMix[hh * 16 + gg];
      uint4 pv = *(const uint4*)&sFSL[tok][hh * 64 + d0];
      u32 pw[4] = {pv.x, pv.y, pv.z, pv.w};
      #pragma unroll
      for (int e = 0; e < 4; ++e) {
        as[e] = fmaf(bf2f((u16)pw[e]), m, as[e]);
        al[e] = fmaf(bf2f((u16)(pw[e] >> 16)), m, al[e]);
      }
    }
    float w0 = sWg[tok][gg][0], w1 = sWg[tok][gg][1], w2 = sWg[tok][gg][2];
    float w3 = sWg[tok][gg][3], w4 = sWg[tok][gg][4];
    float ig = sIdg[tok][gg];
    uint2 dv2 = *(const uint2*)&dOutb[bn * 1024 + idx0];
    uint2 vv2 = *(const uint2*)&sV[tok + 6][idx0];
    uint2 iv2 = *(const uint2*)&qkvi[bn * 4096 + 3072 + idx0];
    float dv[4] = { bf2f((u16)dv2.x), bf2f((u16)(dv2.x >> 16)),
                    bf2f((u16)dv2.y), bf2f((u16)(dv2.y >> 16)) };
    float vv[4] = { bf2f((u16)vv2.x), bf2f((u16)(vv2.x >> 16)),
                    bf2f((u16)vv2.y), bf2f((u16)(vv2.y >> 16)) };
    float iv[4] = { bf2f((u16)iv2.x), bf2f((u16)(iv2.x >> 16)),
                    bf2f((u16)iv2.y), bf2f((u16)(iv2.y >> 16)) };
    uint2 outp;
    u16 o0 = f2bf(w0*as[0] + w1*al[0] + w2*dv[0] + w3*vv[0] + w4*(iv[0]*ig));
    u16 o1 = f2bf(w0*as[1] + w1*al[1] + w2*dv[1] + w3*vv[1] + w4*(iv[1]*ig));
    u16 o2 = f2bf(w0*as[2] + w1*al[2] + w2*dv[2] + w3*vv[2] + w4*(iv[2]*ig));
    u16 o3 = f2bf(w0*as[3] + w1*al[3] + w2*dv[3] + w3*vv[3] + w4*(iv[3]*ig));
    outp.x = (u32)o0 | ((u32)o1 << 16);
    outp.y = (u32)o2 | ((u32)o3 << 16);
    *(uint2*)&ctxb[bn * 1024 + idx0] = outp;
  }
  if (tid == 0) {
    float s = 0.f;
    #pragma unroll
    for (int i = 0; i < 128; ++i) s += sEnt[i];
    atomicAdd(entAcc, s);
  }
}

// ---------------- host launcher ----------------------------------------------
extern "C" void kernel_launch(void* const* d_in, const int* in_sizes, int n_in,
                              void* d_out, int out_size, void* d_ws, size_t ws_size,
                              hipStream_t stream) {
  (void)in_sizes; (void)n_in; (void)out_size; (void)ws_size;
  const float* x       = (const float*)d_in[0];
  const float* W_qkv   = (const float*)d_in[1];
  const float* W_id    = (const float*)d_in[2];
  const float* W_gate  = (const float*)d_in[3];
  const float* b_gate  = (const float*)d_in[4];
  const float* idlog   = (const float*)d_in[5];
  const float* fir_s   = (const float*)d_in[6];
  const float* fir_l   = (const float*)d_in[7];
  const float* mix     = (const float*)d_in[8];
  const float* W_prune = (const float*)d_in[9];
  const float* b_prune = (const float*)d_in[10];
  const float* W_g1    = (const float*)d_in[11];
  const float* b_g1    = (const float*)d_in[12];
  const float* W_g2    = (const float*)d_in[13];
  const float* b_g2    = (const float*)d_in[14];
  const float* W_proj  = (const float*)d_in[15];
  const float* b_proj  = (const float*)d_in[16];
  float* out = (float*)d_out;

  float* ws    = (float*)d_ws;
  float* qkviF = ws;
  float* gp    = ws + 8388608;
  float* g2l   = gp + 393216;
  float* kbF   = g2l + 327680;
  float* wcatF = kbF + 2097152;
  float* catG2F= wcatF + 2686976;
  float* dOb   = catG2F + 65536;
  float* entA  = dOb + 2097152;
  float* cb1   = entA + 8;
  float* cb2   = cb1 + 128;
  float* wprF  = cb2 + 128;

  u16* qkvi   = (u16*)qkviF;
  u16* wcat   = (u16*)wcatF;
  u16* tb16   = (u16*)wcatF;
  u16* catG2  = (u16*)catG2F;
  u16* dOutb  = (u16*)dOb;
  u16* wprojT = (u16*)wprF;
  u16* xb     = (u16*)kbF;
  u16* hb16   = (u16*)dOb;
  u16* ctxb   = (u16*)kbF;

  // 1) fused setup
  setup_k<<<8437, 256, 0, stream>>>(x, W_qkv, W_id, W_g1, W_proj, W_gate,
                                    W_prune, W_g2, b_gate, b_prune, b_g2,
                                    xb, wcat, wprojT, catG2, cb1, cb2, entA);

  // 2) merged qkvi + g1(gelu) + gate/prune: XCD-bijective, B-panel-paired
  gemm_qg<<<656, 512, 0, stream>>>(xb, wcat, b_g1, cb1,
                                   (u16*)qkvi, hb16, gp);

  // 3) g2 logits from gelu output
  gemm_mfma<0,0,0><<<dim3(1, 32), 256, 0, stream>>>(hb16, catG2, cb2, g2l,
      BN_, 128, 1024, 80, nullptr, nullptr);

  // 4) delta prep ; 5) fused scan+output (dv-split x4, XCD-co-located)
  delta_prep<<<1024, 256, 0, stream>>>(qkvi, tb16);
  delta_fused<<<256, 256, 0, stream>>>(tb16, qkvi, dOutb);

  // 6) fused paths + gating
  paths2<<<512, 256, 0, stream>>>(qkvi, dOutb, gp, g2l,
                                  fir_s, fir_l, mix, idlog, ctxb, entA);

  // 7) output projection + entropy scalar
  gemm_mfma<0,0,1><<<dim3(8, 32), 256, 0, stream>>>(ctxb, wprojT, b_proj, out,
      BN_, 1024, 1024, 1024, entA, out + 4194304);
}

// Round 30
// 207.590 us; speedup vs baseline: 1.0113x; 1.0113x over previous
//
#include <hip/hip_runtime.h>
#include <math.h>

#define B_ 4
#define N_ 1024
#define C_ 1024
#define H_ 16
#define D_ 64
#define P_ 5
#define BN_ (B_*N_)
#define TOK 8

typedef unsigned int u32;
typedef unsigned short u16;
typedef __attribute__((ext_vector_type(8))) short bf16x8;
typedef __attribute__((ext_vector_type(4))) float f32x4;

__device__ __forceinline__ float gelu_f(float x){
  float x3 = x*x*x;
  return 0.5f*x*(1.0f + tanhf(0.7978845608028654f*(x + 0.044715f*x3)));
}
__device__ __forceinline__ float sigmoid_f(float x){ return 1.0f/(1.0f+expf(-x)); }

__device__ __forceinline__ u16 f2bf(float f) {
  u32 u = __float_as_uint(f);
  u32 r = u + 0x7fffu + ((u >> 16) & 1u);
  return (u16)(r >> 16);
}
__device__ __forceinline__ float bf2f(u16 v){ return __uint_as_float(((u32)v) << 16); }

__device__ __forceinline__ void gload16(const void* g, void* l) {
  __builtin_amdgcn_global_load_lds((const __attribute__((address_space(1))) u32*)g,
                                   (__attribute__((address_space(3))) u32*)l, 16, 0, 0);
}

// ---- transpose block: fp32 W[K][Nn] tile (r0,c0) -> bf16 Wt[roff+c][K] -------
__device__ __forceinline__ void trans_block(const float* __restrict__ W,
    u16* __restrict__ Wt, int K, int Nn, int roff, int bxx, int byy,
    float (*t)[33], int tid) {
  const int c0 = bxx * 32, r0 = byy * 32;
  const int tx = tid & 31, ty = tid >> 5;
  #pragma unroll
  for (int i = 0; i < 4; ++i) {
    int r = ty + i * 8;
    t[r][tx] = (c0 + tx < Nn) ? W[(size_t)(r0 + r) * Nn + c0 + tx] : 0.f;
  }
  __syncthreads();
  #pragma unroll
  for (int i = 0; i < 4; ++i) {
    int r = ty + i * 8;
    if (c0 + r < Nn)
      Wt[(size_t)(roff + c0 + r) * K + r0 + tx] = f2bf(t[tx][r]);
  }
}

// ---- fused setup: x cast + all weight transposes into wcat + pads + biases ---
__global__ __launch_bounds__(256) void setup_k(const float* __restrict__ x,
    const float* __restrict__ W_qkv, const float* __restrict__ W_id,
    const float* __restrict__ W_g1, const float* __restrict__ W_proj,
    const float* __restrict__ W_gate, const float* __restrict__ W_prune,
    const float* __restrict__ W_g2, const float* __restrict__ bg,
    const float* __restrict__ bp, const float* __restrict__ bg2,
    u16* __restrict__ xb, u16* __restrict__ wcat, u16* __restrict__ wprojT,
    u16* __restrict__ catG2, float* __restrict__ cb1, float* __restrict__ cb2,
    float* __restrict__ entA) {
  __shared__ float t[32][33];
  int bid = blockIdx.x;
  const int tid = threadIdx.x;
  if (bid < 2048) {
    int i = bid * 256 + tid;
    const float4* p = (const float4*)x + (size_t)i * 2;
    float4 a = p[0], b = p[1];
    uint4 o;
    o.x = (u32)f2bf(a.x) | ((u32)f2bf(a.y) << 16);
    o.y = (u32)f2bf(a.z) | ((u32)f2bf(a.w) << 16);
    o.z = (u32)f2bf(b.x) | ((u32)f2bf(b.y) << 16);
    o.w = (u32)f2bf(b.z) | ((u32)f2bf(b.w) << 16);
    *(uint4*)(xb + (size_t)i * 8) = o;
    return;
  }
  bid -= 2048;
  if (bid < 3072) { trans_block(W_qkv, wcat, 1024, 3072, 0, bid % 96, bid / 96, t, tid); return; }
  bid -= 3072;
  if (bid < 1024) { trans_block(W_id, wcat, 1024, 1024, 3072, bid & 31, bid >> 5, t, tid); return; }
  bid -= 1024;
  if (bid < 1024) { trans_block(W_g1, wcat, 1024, 1024, 4096, bid & 31, bid >> 5, t, tid); return; }
  bid -= 1024;
  if (bid < 1024) { trans_block(W_proj, wprojT, 1024, 1024, 0, bid & 31, bid >> 5, t, tid); return; }
  bid -= 1024;
  if (bid < 32)  { trans_block(W_gate, wcat, 1024, 16, 5120, 0, bid, t, tid); return; }
  bid -= 32;
  if (bid < 96)  { trans_block(W_prune, wcat, 1024, 80, 5136, bid % 3, bid / 3, t, tid); return; }
  bid -= 96;
  if (bid < 96)  { trans_block(W_g2, catG2, 1024, 80, 0, bid % 3, bid / 3, t, tid); return; }
  bid -= 96;
  if (bid < 8) {
    int idx = (bid * 256 + tid) * 16;
    *(uint4*)(wcat + (size_t)5216 * 1024 + idx) = make_uint4(0, 0, 0, 0);
    *(uint4*)(wcat + (size_t)5216 * 1024 + idx + 8) = make_uint4(0, 0, 0, 0);
    return;
  }
  bid -= 8;
  if (bid < 12) {
    int idx = (bid * 256 + tid) * 16;
    *(uint4*)(catG2 + 80 * 1024 + idx) = make_uint4(0, 0, 0, 0);
    *(uint4*)(catG2 + 80 * 1024 + idx + 8) = make_uint4(0, 0, 0, 0);
    return;
  }
  if (tid < 128) cb1[tid] = (tid < 16) ? bg[tid] : (tid < 96 ? bp[tid - 16] : 0.f);
  else { int c = tid - 128; cb2[c] = (c < 80) ? bg2[c] : 0.f; }
  if (tid == 0) entA[0] = 0.f;
}

// ---- merged qkvi+g1+gate/prune GEMM: xb @ wcat (N=5248), routed epilogue -----
// 1D grid 656 = 8 XCD x 82, XCD-bijective remap: half = (slot>=41), bx = slot-41*half.
// Mapping study (R25-R29): this (R28) config is fastest at 81 us / FETCH 67 MB /
// WRITE 44 MB. B-panel pairing (half=slot&1) cut FETCH to 50 MB but raised
// WRITE to 59 MB (interleaved row-panel stores break write-combining) -> 85 us.
// 2-buffer co-residency (R27) desynced blocks, FETCH 326 MB -> 256 us.
// Keep: 3-buffer counted vmcnt + sequential per-XCD write stream.
__global__ __launch_bounds__(512, 4) void gemm_qg(const u16* __restrict__ A,
    const u16* __restrict__ Bt, const float* __restrict__ b_g1,
    const float* __restrict__ cb1, u16* __restrict__ qkviOut,
    u16* __restrict__ hb16, float* __restrict__ gp) {
  __shared__ __align__(16) u16 lA[3][256 * 32];
  __shared__ __align__(16) u16 lB[3][128 * 32];
  const int tid = threadIdx.x;
  const int lane = tid & 63, wid = tid >> 6;      // 0..7
  const int wr = wid >> 1, wc = wid & 1;
  const int r16 = lane & 15, kq = lane >> 4;
  const int ib = blockIdx.x;
  const int xcd = ib & 7, slot = ib >> 3;          // 82 slots per XCD
  const int half = (slot >= 41) ? 1 : 0;
  const int by = xcd * 2 + half;
  const int bx = slot - (half ? 41 : 0);
  const int row0 = by * 256, col0 = bx * 128;
  const int srow = lane >> 2;
  const int skoff = (((lane & 3) ^ ((srow >> 1) & 3)) << 3);
  const int rsw = ((r16 >> 1) & 3);
  const int K = 1024, T = 32;

  #define STAGE2(buf, tk) { \
    const int k0_ = (tk) << 5; \
    _Pragma("unroll") \
    for (int s = 0; s < 2; ++s) { \
      int c = wid * 2 + s; \
      int rt = c * 16 + srow; \
      gload16(A + (size_t)(row0 + rt) * K + k0_ + skoff, &lA[buf][c * 512]); \
    } \
    { \
      int rtB = wid * 16 + srow; \
      gload16(Bt + (size_t)(col0 + rtB) * K + k0_ + skoff, &lB[buf][wid * 512]); \
    } }

  f32x4 acc[4][4] = {};
  STAGE2(0, 0);
  STAGE2(1, 1);

  for (int t = 0; t < T; ++t) {
    if (t < T - 1) asm volatile("s_waitcnt vmcnt(3)" ::: "memory");
    else           asm volatile("s_waitcnt vmcnt(0)" ::: "memory");
    __builtin_amdgcn_s_barrier();
    asm volatile("" ::: "memory");
    if (t + 2 < T) { const int bnx = (t + 2) % 3; STAGE2(bnx, t + 2); }
    const int bc = t % 3;
    const int ko = ((kq ^ rsw) << 3);
    bf16x8 af[4], bfv[4];
    #pragma unroll
    for (int m = 0; m < 4; ++m)
      af[m] = *(const bf16x8*)&lA[bc][(wr * 64 + m * 16 + r16) * 32 + ko];
    #pragma unroll
    for (int n = 0; n < 4; ++n)
      bfv[n] = *(const bf16x8*)&lB[bc][(wc * 64 + n * 16 + r16) * 32 + ko];
    #pragma unroll
    for (int m = 0; m < 4; ++m)
      #pragma unroll
      for (int n = 0; n < 4; ++n)
        acc[m][n] = __builtin_amdgcn_mfma_f32_16x16x32_bf16(af[m], bfv[n], acc[m][n], 0, 0, 0);
  }
  #undef STAGE2

  if (col0 < 4096) {
    // ---- qkvi region: q/k l2norm + bf16 store ----
    const int hb = (col0 + wc * 64) >> 6;
    if (hb < 32) {
      float sc[4][4];
      #pragma unroll
      for (int m = 0; m < 4; ++m)
        #pragma unroll
        for (int r = 0; r < 4; ++r) {
          float s = 0.f;
          #pragma unroll
          for (int n = 0; n < 4; ++n) s = fmaf(acc[m][n][r], acc[m][n][r], s);
          s += __shfl_xor(s, 1); s += __shfl_xor(s, 2);
          s += __shfl_xor(s, 4); s += __shfl_xor(s, 8);
          float tsc = rsqrtf(s + 1e-6f);
          sc[m][r] = (hb < 16) ? tsc * 0.125f : tsc;
        }
      #pragma unroll
      for (int m = 0; m < 4; ++m)
        #pragma unroll
        for (int n = 0; n < 4; ++n)
          #pragma unroll
          for (int r = 0; r < 4; ++r) acc[m][n][r] *= sc[m][r];
    }
    #pragma unroll
    for (int n = 0; n < 4; ++n) {
      int col = col0 + wc * 64 + n * 16 + r16;
      #pragma unroll
      for (int m = 0; m < 4; ++m) {
        int rowb = row0 + wr * 64 + m * 16 + kq * 4;
        #pragma unroll
        for (int r = 0; r < 4; ++r)
          qkviOut[(size_t)(rowb + r) * 4096 + col] = f2bf(acc[m][n][r]);
      }
    }
  } else {
    // ---- g1 / gate+prune region ----
    #pragma unroll
    for (int n = 0; n < 4; ++n) {
      const int col = col0 + wc * 64 + n * 16 + r16;
      if (col < 5120) {
        const int c1 = col - 4096;
        const float bs = b_g1[c1];
        #pragma unroll
        for (int m = 0; m < 4; ++m) {
          int rowb = row0 + wr * 64 + m * 16 + kq * 4;
          #pragma unroll
          for (int r = 0; r < 4; ++r)
            hb16[(size_t)(rowb + r) * 1024 + c1] = f2bf(gelu_f(acc[m][n][r] + bs));
        }
      } else if (col < 5216) {
        const int c2 = col - 5120;
        const float bs = cb1[c2];
        #pragma unroll
        for (int m = 0; m < 4; ++m) {
          int rowb = row0 + wr * 64 + m * 16 + kq * 4;
          #pragma unroll
          for (int r = 0; r < 4; ++r)
            gp[(size_t)(rowb + r) * 96 + c2] = acc[m][n][r] + bs;
        }
      }
    }
  }
}

// ------ bf16 MFMA GEMM 128^2, 3-buffer pipelined + swizzle (g2l, proj) --------
template<int ACT, int OBF, int ENT>
__global__ __launch_bounds__(256) void gemm_mfma(const u16* __restrict__ A,
    const u16* __restrict__ Bt, const float* __restrict__ bias,
    float* __restrict__ Cout, int M, int Nn, int K, int Ns,
    const float* __restrict__ entSrc, float* __restrict__ entDst) {
  __shared__ __align__(16) u16 lA[3][128 * 32];
  __shared__ __align__(16) u16 lB[3][128 * 32];
  const int tid = threadIdx.x;
  const int lane = tid & 63, wid = tid >> 6;
  const int wr = wid >> 1, wc = wid & 1;
  const int r16 = lane & 15, kq = lane >> 4;
  const int row0 = blockIdx.y * 128, col0 = blockIdx.x * 128;
  const int c0 = wid * 2;
  const int srow = lane >> 2;
  const int skoff = (((lane & 3) ^ ((srow >> 1) & 3)) << 3);
  const int rsw = ((r16 >> 1) & 3);
  const int T = K >> 5;

  if (ENT && blockIdx.x == 0 && blockIdx.y == 0 && tid == 0)
    entDst[0] = entSrc[0] * (1.0f / 65536.0f);

  #define STAGE_T(buf, tk) { \
    const int k0_ = (tk) << 5; \
    _Pragma("unroll") \
    for (int s = 0; s < 2; ++s) { \
      int c = c0 + s; \
      int rt = c * 16 + srow; \
      gload16(A  + (size_t)(row0 + rt) * K + k0_ + skoff, &lA[buf][c * 512]); \
      gload16(Bt + (size_t)(col0 + rt) * K + k0_ + skoff, &lB[buf][c * 512]); \
    } }

  f32x4 acc[4][4] = {};
  STAGE_T(0, 0);
  if (T > 1) STAGE_T(1, 1);

  for (int t = 0; t < T; ++t) {
    if (t < T - 1) asm volatile("s_waitcnt vmcnt(4)" ::: "memory");
    else           asm volatile("s_waitcnt vmcnt(0)" ::: "memory");
    __builtin_amdgcn_s_barrier();
    asm volatile("" ::: "memory");
    if (t + 2 < T) { const int bnx = (t + 2) % 3; STAGE_T(bnx, t + 2); }
    const int bc = t % 3;
    const int ko = ((kq ^ rsw) << 3);
    bf16x8 af[4], bfv[4];
    #pragma unroll
    for (int m = 0; m < 4; ++m)
      af[m] = *(const bf16x8*)&lA[bc][(wr * 64 + m * 16 + r16) * 32 + ko];
    #pragma unroll
    for (int n = 0; n < 4; ++n)
      bfv[n] = *(const bf16x8*)&lB[bc][(wc * 64 + n * 16 + r16) * 32 + ko];
    #pragma unroll
    for (int m = 0; m < 4; ++m)
      #pragma unroll
      for (int n = 0; n < 4; ++n)
        acc[m][n] = __builtin_amdgcn_mfma_f32_16x16x32_bf16(af[m], bfv[n], acc[m][n], 0, 0, 0);
  }
  #undef STAGE_T

  #pragma unroll
  for (int n = 0; n < 4; ++n) {
    int col = col0 + wc * 64 + n * 16 + r16;
    if (col >= Ns) continue;
    float bs = bias ? bias[col] : 0.0f;
    #pragma unroll
    for (int m = 0; m < 4; ++m) {
      int rowb = row0 + wr * 64 + m * 16 + kq * 4;
      #pragma unroll
      for (int r = 0; r < 4; ++r) {
        float v = acc[m][n][r] + bs;
        if (ACT == 1) v = gelu_f(v);
        if (OBF) ((u16*)Cout)[(size_t)(rowb + r) * Ns + col] = f2bf(v);
        else     Cout[(size_t)(rowb + r) * Ns + col] = v;
      }
    }
  }
}

// ------- DeltaNet prep: M via MFMA from normalized k̂ (qkvi), T' solve --------
__global__ __launch_bounds__(256) void delta_prep(const u16* __restrict__ qkvi,
    u16* __restrict__ tb) {
  const int bx = blockIdx.x;
  const int bh = bx >> 4, g = bx & 15;
  const int b = bh >> 4, h = bh & 15;
  const int n0 = g * 64;
  const int tid = threadIdx.x;
  __shared__ __align__(16) u16 sKb[64][72];
  __shared__ __align__(16) float sMT[64][68];
  __shared__ float sBeta[64];

  if (tid < 64) sBeta[tid] = 1.0f - 0.9f * (float)(n0 + tid) / 1023.0f;

  const int fr = tid >> 2, fe0 = (tid & 3) * 16;
  const size_t krow = ((size_t)b * N_ + n0 + fr) * 4096 + 1024 + h * 64 + fe0;
  *(uint4*)&sKb[fr][fe0]     = *(const uint4*)(qkvi + krow);
  *(uint4*)&sKb[fr][fe0 + 8] = *(const uint4*)(qkvi + krow + 8);
  __syncthreads();

  {
    const int lane = tid & 63, wv = tid >> 6;
    const int l15 = lane & 15, l4 = lane >> 4;
    bf16x8 ka0 = *(const bf16x8*)&sKb[16*wv + l15][l4*8];
    bf16x8 ka1 = *(const bf16x8*)&sKb[16*wv + l15][32 + l4*8];
    #pragma unroll
    for (int ct = 0; ct < 4; ++ct) {
      bf16x8 kc0 = *(const bf16x8*)&sKb[ct*16 + l15][l4*8];
      bf16x8 kc1 = *(const bf16x8*)&sKb[ct*16 + l15][32 + l4*8];
      f32x4 m = {};
      m = __builtin_amdgcn_mfma_f32_16x16x32_bf16(ka0, kc0, m, 0, 0, 0);
      m = __builtin_amdgcn_mfma_f32_16x16x32_bf16(ka1, kc1, m, 0, 0, 0);
      const int c = ct*16 + l15, rbase = 16*wv + l4*4;
      float4 o;
      o.x = (rbase+0 > c) ? sBeta[rbase+0] * m[0] : 0.f;
      o.y = (rbase+1 > c) ? sBeta[rbase+1] * m[1] : 0.f;
      o.z = (rbase+2 > c) ? sBeta[rbase+2] * m[2] : 0.f;
      o.w = (rbase+3 > c) ? sBeta[rbase+3] * m[3] : 0.f;
      *(float4*)&sMT[c][rbase] = o;
    }
  }
  __syncthreads();

  if (tid < 64) {
    const int c = tid;
    float a[64];
    #pragma unroll
    for (int i = 0; i < 64; ++i) a[i] = (i == c) ? 1.f : 0.f;
    #pragma unroll
    for (int ib = 0; ib < 4; ++ib) {
      #pragma unroll
      for (int i2 = 0; i2 < 16; ++i2) {
        const int i = ib * 16 + i2;
        const float wi = a[i];
        #pragma unroll
        for (int j4 = ib * 4; j4 < 16; ++j4) {
          const float4 m = *(const float4*)&sMT[i][j4 * 4];
          a[j4*4+0] = fmaf(-m.x, wi, a[j4*4+0]);
          a[j4*4+1] = fmaf(-m.y, wi, a[j4*4+1]);
          a[j4*4+2] = fmaf(-m.z, wi, a[j4*4+2]);
          a[j4*4+3] = fmaf(-m.w, wi, a[j4*4+3]);
        }
      }
    }
    const float bc = sBeta[c];
    const size_t obase = (size_t)bx * 4096;
    #pragma unroll
    for (int i = 0; i < 64; ++i) tb[obase + i * 64 + c] = f2bf(a[i] * bc);
  }
}

// -------- DeltaNet fused scan+output, dv-split x4, XCD-co-located quarters ----
__global__ __launch_bounds__(256, 1) void delta_fused(const u16* __restrict__ tb,
    const u16* __restrict__ qkvi, u16* __restrict__ dOutb) {
  const int bh = blockIdx.x & 63, q4 = blockIdx.x >> 6;
  const int b = bh >> 4, h = bh & 15;
  const int dvo = q4 * 16;
  const int tid = threadIdx.x;
  const int lane = tid & 63, wv = tid >> 6;
  const int l15 = lane & 15, l4 = lane >> 4;
  const int fr = tid >> 2, fe0 = (tid & 3) * 16;
  const int fe2 = (tid & 3) * 4;

  __shared__ __align__(16) u16 sK [64][72];
  __shared__ __align__(16) u16 sKT[64][72];
  __shared__ __align__(16) u16 sT [64][72];
  __shared__ __align__(16) u16 sQ [64][72];
  __shared__ __align__(16) u16 sV [64][24];
  __shared__ __align__(16) u16 sSt[16][72];
  __shared__ __align__(16) u16 sYt[16][72];
  __shared__ __align__(16) u16 sUt[16][72];
  __shared__ __align__(16) u16 sA [64][72];

  f32x4 Sacc = {};

  uint4 pk0, pk1, pt0, pt1, pq0, pq1;
  uint2 pv0;
  {
    const size_t bs = (size_t)(bh * 16) * 4096;
    const size_t rowq = ((size_t)(b * 1024 + fr)) * 4096 + h * 64 + fe0;
    const size_t rowv = ((size_t)(b * 1024 + fr)) * 4096 + 2048 + h * 64 + dvo + fe2;
    pq0 = *(const uint4*)(qkvi + rowq);        pq1 = *(const uint4*)(qkvi + rowq + 8);
    pk0 = *(const uint4*)(qkvi + rowq + 1024); pk1 = *(const uint4*)(qkvi + rowq + 1024 + 8);
    pv0 = *(const uint2*)(qkvi + rowv);
    pt0 = *(const uint4*)(tb + bs + tid*16);   pt1 = *(const uint4*)(tb + bs + tid*16 + 8);
  }

  for (int g = 0; g < 16; ++g) {
    __syncthreads();
    *(uint4*)&sK[fr][fe0] = pk0; *(uint4*)&sK[fr][fe0+8] = pk1;
    *(uint4*)&sT[fr][fe0] = pt0; *(uint4*)&sT[fr][fe0+8] = pt1;
    *(uint4*)&sQ[fr][fe0] = pq0; *(uint4*)&sQ[fr][fe0+8] = pq1;
    *(uint2*)&sV[fr][fe2] = pv0;
    {
      u32 kk[8] = {pk0.x, pk0.y, pk0.z, pk0.w, pk1.x, pk1.y, pk1.z, pk1.w};
      #pragma unroll
      for (int i = 0; i < 8; ++i) {
        sKT[fe0 + 2*i][fr]     = (u16)kk[i];
        sKT[fe0 + 2*i + 1][fr] = (u16)(kk[i] >> 16);
      }
    }
    {
      u32 lo = (u32)f2bf(Sacc[0]) | ((u32)f2bf(Sacc[1]) << 16);
      u32 hi = (u32)f2bf(Sacc[2]) | ((u32)f2bf(Sacc[3]) << 16);
      *(u32*)&sSt[l15][16*wv + l4*4]     = lo;
      *(u32*)&sSt[l15][16*wv + l4*4 + 2] = hi;
    }
    __syncthreads();
    if (g < 15) {
      const size_t bs = (size_t)(bh * 16 + g + 1) * 4096;
      const size_t rowq = ((size_t)(b * 1024 + (g + 1) * 64 + fr)) * 4096 + h * 64 + fe0;
      const size_t rowv = ((size_t)(b * 1024 + (g + 1) * 64 + fr)) * 4096 + 2048 + h * 64 + dvo + fe2;
      pq0 = *(const uint4*)(qkvi + rowq);        pq1 = *(const uint4*)(qkvi + rowq + 8);
      pk0 = *(const uint4*)(qkvi + rowq + 1024); pk1 = *(const uint4*)(qkvi + rowq + 1024 + 8);
      pv0 = *(const uint2*)(qkvi + rowv);
      pt0 = *(const uint4*)(tb + bs + tid*16);   pt1 = *(const uint4*)(tb + bs + tid*16 + 8);
    }
    bf16x8 qf0 = *(const bf16x8*)&sQ[16*wv + l15][l4*8];
    bf16x8 qf1 = *(const bf16x8*)&sQ[16*wv + l15][32 + l4*8];
    bf16x8 kr0 = *(const bf16x8*)&sK[16*wv + l15][l4*8];
    bf16x8 kr1 = *(const bf16x8*)&sK[16*wv + l15][32 + l4*8];
    f32x4 aacc[4] = {}, yacc = {}, oacc = {};
    #pragma unroll
    for (int ct = 0; ct < 4; ++ct) {
      bf16x8 kc0 = *(const bf16x8*)&sK[ct*16 + l15][l4*8];
      bf16x8 kc1 = *(const bf16x8*)&sK[ct*16 + l15][32 + l4*8];
      aacc[ct] = __builtin_amdgcn_mfma_f32_16x16x32_bf16(qf0, kc0, aacc[ct], 0, 0, 0);
      aacc[ct] = __builtin_amdgcn_mfma_f32_16x16x32_bf16(qf1, kc1, aacc[ct], 0, 0, 0);
    }
    {
      bf16x8 s0 = *(const bf16x8*)&sSt[l15][l4*8];
      bf16x8 s1 = *(const bf16x8*)&sSt[l15][32 + l4*8];
      yacc = __builtin_amdgcn_mfma_f32_16x16x32_bf16(kr0, s0, yacc, 0, 0, 0);
      yacc = __builtin_amdgcn_mfma_f32_16x16x32_bf16(kr1, s1, yacc, 0, 0, 0);
      oacc = __builtin_amdgcn_mfma_f32_16x16x32_bf16(qf0, s0, oacc, 0, 0, 0);
      oacc = __builtin_amdgcn_mfma_f32_16x16x32_bf16(qf1, s1, oacc, 0, 0, 0);
    }
    {
      float y0 = bf2f(sV[16*wv + l4*4 + 0][l15]) - yacc[0];
      float y1 = bf2f(sV[16*wv + l4*4 + 1][l15]) - yacc[1];
      float y2 = bf2f(sV[16*wv + l4*4 + 2][l15]) - yacc[2];
      float y3 = bf2f(sV[16*wv + l4*4 + 3][l15]) - yacc[3];
      u32 lo = (u32)f2bf(y0) | ((u32)f2bf(y1) << 16);
      u32 hi = (u32)f2bf(y2) | ((u32)f2bf(y3) << 16);
      *(u32*)&sYt[l15][16*wv + l4*4]     = lo;
      *(u32*)&sYt[l15][16*wv + l4*4 + 2] = hi;
    }
    #pragma unroll
    for (int ct = 0; ct < 4; ++ct)
      #pragma unroll
      for (int j = 0; j < 4; ++j) {
        int r = 16*wv + l4*4 + j, c = ct*16 + l15;
        sA[r][c] = f2bf((r >= c) ? aacc[ct][j] : 0.f);
      }
    __syncthreads();
    bf16x8 tf0 = *(const bf16x8*)&sT[16*wv + l15][l4*8];
    bf16x8 tf1 = *(const bf16x8*)&sT[16*wv + l15][32 + l4*8];
    f32x4 uacc = {};
    {
      bf16x8 y0 = *(const bf16x8*)&sYt[l15][l4*8];
      bf16x8 y1 = *(const bf16x8*)&sYt[l15][32 + l4*8];
      uacc = __builtin_amdgcn_mfma_f32_16x16x32_bf16(tf0, y0, uacc, 0, 0, 0);
      uacc = __builtin_amdgcn_mfma_f32_16x16x32_bf16(tf1, y1, uacc, 0, 0, 0);
    }
    {
      u32 lo = (u32)f2bf(uacc[0]) | ((u32)f2bf(uacc[1]) << 16);
      u32 hi = (u32)f2bf(uacc[2]) | ((u32)f2bf(uacc[3]) << 16);
      *(u32*)&sUt[l15][16*wv + l4*4]     = lo;
      *(u32*)&sUt[l15][16*wv + l4*4 + 2] = hi;
    }
    __syncthreads();
    bf16x8 af0 = *(const bf16x8*)&sA[16*wv + l15][l4*8];
    bf16x8 af1 = *(const bf16x8*)&sA[16*wv + l15][32 + l4*8];
    bf16x8 kt0 = *(const bf16x8*)&sKT[16*wv + l15][l4*8];
    bf16x8 kt1 = *(const bf16x8*)&sKT[16*wv + l15][32 + l4*8];
    {
      bf16x8 u0 = *(const bf16x8*)&sUt[l15][l4*8];
      bf16x8 u1 = *(const bf16x8*)&sUt[l15][32 + l4*8];
      oacc = __builtin_amdgcn_mfma_f32_16x16x32_bf16(af0, u0, oacc, 0, 0, 0);
      oacc = __builtin_amdgcn_mfma_f32_16x16x32_bf16(af1, u1, oacc, 0, 0, 0);
      Sacc = __builtin_amdgcn_mfma_f32_16x16x32_bf16(kt0, u0, Sacc, 0, 0, 0);
      Sacc = __builtin_amdgcn_mfma_f32_16x16x32_bf16(kt1, u1, Sacc, 0, 0, 0);
    }
    #pragma unroll
    for (int j = 0; j < 4; ++j) {
      int r = 16*wv + l4*4 + j;
      dOutb[((size_t)(b * 1024 + g * 64 + r)) * 1024 + h * 64 + dvo + l15] = f2bf(oacc[j]);
    }
  }
}

// ------- fused FIR + mix + gating + ctx; contiguous 4-elem ownership ----------
__global__ __launch_bounds__(256) void paths2(const u16* __restrict__ qkvi,
    const u16* __restrict__ dOutb, const float* __restrict__ gp,
    const float* __restrict__ g2L, const float* __restrict__ fir_s,
    const float* __restrict__ fir_l, const float* __restrict__ mix,
    const float* __restrict__ idlog, u16* __restrict__ ctxb,
    float* __restrict__ entAcc) {
  const int bid = ((blockIdx.x & 7) << 6) | (blockIdx.x >> 3);
  const int b = bid >> 7, n0 = (bid & 127) * TOK;
  const int tid = threadIdx.x;
  __shared__ u16 sV[TOK + 6][1024];
  __shared__ u32 sFSL[TOK][1024];           // packed: fs | fl<<16
  __shared__ float sMix[256];
  __shared__ float sWg[TOK][16][5];
  __shared__ float sIdg[TOK][16];
  __shared__ float sEnt[128];
  sMix[tid] = mix[tid];

  #pragma unroll
  for (int i = 0; i < 7; ++i) {
    int r = i * 2 + (tid >> 7);
    int t = n0 - 6 + r;
    int col = (tid & 127) * 8;
    uint4 v = make_uint4(0, 0, 0, 0);
    if (t >= 0)
      v = *(const uint4*)(qkvi + ((size_t)b * 1024 + t) * 4096 + 2048 + col);
    *(uint4*)&sV[r][col] = v;
  }

  if (tid < 128) {
    const int tok = tid >> 4, hh = tid & 15;
    const size_t bn = (size_t)b * 1024 + n0 + tok;
    float pl[5], lp[5];
    #pragma unroll
    for (int p = 0; p < 5; ++p) pl[p] = gp[bn * 96 + 16 + hh * 5 + p];
    float mx = pl[0];
    #pragma unroll
    for (int p = 1; p < 5; ++p) mx = fmaxf(mx, pl[p]);
    float s = 0.f;
    #pragma unroll
    for (int p = 0; p < 5; ++p) { pl[p] = expf(pl[p] - mx); s += pl[p]; }
    float inv = 1.f / s, e1 = 0.f;
    #pragma unroll
    for (int p = 0; p < 5; ++p) {
      float prob = pl[p] * inv;
      lp[p] = logf(prob + 1e-8f);
      e1 -= prob * lp[p];
    }
    float gl[5];
    #pragma unroll
    for (int p = 0; p < 5; ++p) gl[p] = g2L[bn * 80 + hh * 5 + p] + lp[p];
    float mx2 = gl[0];
    #pragma unroll
    for (int p = 1; p < 5; ++p) mx2 = fmaxf(mx2, gl[p]);
    float s2 = 0.f;
    #pragma unroll
    for (int p = 0; p < 5; ++p) { gl[p] = expf(gl[p] - mx2); s2 += gl[p]; }
    float inv2 = 1.f / s2, e2 = 0.f;
    #pragma unroll
    for (int p = 0; p < 5; ++p) {
      float w = gl[p] * inv2;
      sWg[tok][hh][p] = w;
      e2 -= w * logf(w + 1e-8f);
    }
    sEnt[tid] = e1 + e2;
    sIdg[tok][hh] = sigmoid_f(gp[bn * 96 + hh]) * sigmoid_f(idlog[hh]);
  }
  __syncthreads();

  const int idx0 = tid * 4;                // 4 consecutive elems, same head
  const int gg = idx0 >> 6, d0 = idx0 & 63;

  // FIR: b64 tap reads, b128 packed write
  {
    float fl7[4][7], fs3[4][3];
    #pragma unroll
    for (int e = 0; e < 4; ++e) {
      #pragma unroll
      for (int j = 0; j < 7; ++j) fl7[e][j] = fir_l[(size_t)(idx0 + e) * 7 + j];
      #pragma unroll
      for (int j = 0; j < 3; ++j) fs3[e][j] = fir_s[(size_t)(idx0 + e) * 3 + j];
    }
    #pragma unroll
    for (int tok = 0; tok < TOK; ++tok) {
      float accs[4] = {}, accl[4] = {};
      #pragma unroll
      for (int j = 0; j < 7; ++j) {
        uint2 v2 = *(const uint2*)&sV[tok + j][idx0];
        float vv[4] = { bf2f((u16)v2.x), bf2f((u16)(v2.x >> 16)),
                        bf2f((u16)v2.y), bf2f((u16)(v2.y >> 16)) };
        #pragma unroll
        for (int e = 0; e < 4; ++e) {
          accl[e] = fmaf(fl7[e][j], vv[e], accl[e]);
          if (j >= 4) accs[e] = fmaf(fs3[e][j - 4], vv[e], accs[e]);
        }
      }
      uint4 pk;
      pk.x = (u32)f2bf(accs[0]) | ((u32)f2bf(accl[0]) << 16);
      pk.y = (u32)f2bf(accs[1]) | ((u32)f2bf(accl[1]) << 16);
      pk.z = (u32)f2bf(accs[2]) | ((u32)f2bf(accl[2]) << 16);
      pk.w = (u32)f2bf(accs[3]) | ((u32)f2bf(accl[3]) << 16);
      *(uint4*)&sFSL[tok][idx0] = pk;
    }
  }
  __syncthreads();

  // mix + combine: b128 gathers, b64 global IO
  #pragma unroll
  for (int tok = 0; tok < TOK; ++tok) {
    const size_t bn = (size_t)b * 1024 + n0 + tok;
    uint4 own = *(const uint4*)&sFSL[tok][idx0];
    u32 ow[4] = {own.x, own.y, own.z, own.w};
    float as[4], al[4];
    #pragma unroll
    for (int e = 0; e < 4; ++e) { as[e] = bf2f((u16)ow[e]); al[e] = bf2f((u16)(ow[e] >> 16)); }
    #pragma unroll
    for (int hh = 0; hh < 16; ++hh) {
      float m = sMix[hh * 16 + gg];
      uint4 pv = *(const uint4*)&sFSL[tok][hh * 64 + d0];
      u32 pw[4] = {pv.x, pv.y, pv.z, pv.w};
      #pragma unroll
      for (int e = 0; e < 4; ++e) {
        as[e] = fmaf(bf2f((u16)pw[e]), m, as[e]);
        al[e] = fmaf(bf2f((u16)(pw[e] >> 16)), m, al[e]);
      }
    }
    float w0 = sWg[tok][gg][0], w1 = sWg[tok][gg][1], w2 = sWg[tok][gg][2];
    float w3 = sWg[tok][gg][3], w4 = sWg[tok][gg][4];
    float ig = sIdg[tok][gg];
    uint2 dv2 = *(const uint2*)&dOutb[bn * 1024 + idx0];
    uint2 vv2 = *(const uint2*)&sV[tok + 6][idx0];
    uint2 iv2 = *(const uint2*)&qkvi[bn * 4096 + 3072 + idx0];
    float dv[4] = { bf2f((u16)dv2.x), bf2f((u16)(dv2.x >> 16)),
                    bf2f((u16)dv2.y), bf2f((u16)(dv2.y >> 16)) };
    float vv[4] = { bf2f((u16)vv2.x), bf2f((u16)(vv2.x >> 16)),
                    bf2f((u16)vv2.y), bf2f((u16)(vv2.y >> 16)) };
    float iv[4] = { bf2f((u16)iv2.x), bf2f((u16)(iv2.x >> 16)),
                    bf2f((u16)iv2.y), bf2f((u16)(iv2.y >> 16)) };
    uint2 outp;
    u16 o0 = f2bf(w0*as[0] + w1*al[0] + w2*dv[0] + w3*vv[0] + w4*(iv[0]*ig));
    u16 o1 = f2bf(w0*as[1] + w1*al[1] + w2*dv[1] + w3*vv[1] + w4*(iv[1]*ig));
    u16 o2 = f2bf(w0*as[2] + w1*al[2] + w2*dv[2] + w3*vv[2] + w4*(iv[2]*ig));
    u16 o3 = f2bf(w0*as[3] + w1*al[3] + w2*dv[3] + w3*vv[3] + w4*(iv[3]*ig));
    outp.x = (u32)o0 | ((u32)o1 << 16);
    outp.y = (u32)o2 | ((u32)o3 << 16);
    *(uint2*)&ctxb[bn * 1024 + idx0] = outp;
  }
  if (tid == 0) {
    float s = 0.f;
    #pragma unroll
    for (int i = 0; i < 128; ++i) s += sEnt[i];
    atomicAdd(entAcc, s);
  }
}

// ---------------- host launcher ----------------------------------------------
extern "C" void kernel_launch(void* const* d_in, const int* in_sizes, int n_in,
                              void* d_out, int out_size, void* d_ws, size_t ws_size,
                              hipStream_t stream) {
  (void)in_sizes; (void)n_in; (void)out_size; (void)ws_size;
  const float* x       = (const float*)d_in[0];
  const float* W_qkv   = (const float*)d_in[1];
  const float* W_id    = (const float*)d_in[2];
  const float* W_gate  = (const float*)d_in[3];
  const float* b_gate  = (const float*)d_in[4];
  const float* idlog   = (const float*)d_in[5];
  const float* fir_s   = (const float*)d_in[6];
  const float* fir_l   = (const float*)d_in[7];
  const float* mix     = (const float*)d_in[8];
  const float* W_prune = (const float*)d_in[9];
  const float* b_prune = (const float*)d_in[10];
  const float* W_g1    = (const float*)d_in[11];
  const float* b_g1    = (const float*)d_in[12];
  const float* W_g2    = (const float*)d_in[13];
  const float* b_g2    = (const float*)d_in[14];
  const float* W_proj  = (const float*)d_in[15];
  const float* b_proj  = (const float*)d_in[16];
  float* out = (float*)d_out;

  float* ws    = (float*)d_ws;
  float* qkviF = ws;
  float* gp    = ws + 8388608;
  float* g2l   = gp + 393216;
  float* kbF   = g2l + 327680;
  float* wcatF = kbF + 2097152;
  float* catG2F= wcatF + 2686976;
  float* dOb   = catG2F + 65536;
  float* entA  = dOb + 2097152;
  float* cb1   = entA + 8;
  float* cb2   = cb1 + 128;
  float* wprF  = cb2 + 128;

  u16* qkvi   = (u16*)qkviF;
  u16* wcat   = (u16*)wcatF;
  u16* tb16   = (u16*)wcatF;
  u16* catG2  = (u16*)catG2F;
  u16* dOutb  = (u16*)dOb;
  u16* wprojT = (u16*)wprF;
  u16* xb     = (u16*)kbF;
  u16* hb16   = (u16*)dOb;
  u16* ctxb   = (u16*)kbF;

  // 1) fused setup
  setup_k<<<8437, 256, 0, stream>>>(x, W_qkv, W_id, W_g1, W_proj, W_gate,
                                    W_prune, W_g2, b_gate, b_prune, b_g2,
                                    xb, wcat, wprojT, catG2, cb1, cb2, entA);

  // 2) merged qkvi + g1(gelu) + gate/prune: XCD-bijective 1D grid (656 = 8x82)
  gemm_qg<<<656, 512, 0, stream>>>(xb, wcat, b_g1, cb1,
                                   (u16*)qkvi, hb16, gp);

  // 3) g2 logits from gelu output
  gemm_mfma<0,0,0><<<dim3(1, 32), 256, 0, stream>>>(hb16, catG2, cb2, g2l,
      BN_, 128, 1024, 80, nullptr, nullptr);

  // 4) delta prep ; 5) fused scan+output (dv-split x4, XCD-co-located)
  delta_prep<<<1024, 256, 0, stream>>>(qkvi, tb16);
  delta_fused<<<256, 256, 0, stream>>>(tb16, qkvi, dOutb);

  // 6) fused paths + gating
  paths2<<<512, 256, 0, stream>>>(qkvi, dOutb, gp, g2l,
                                  fir_s, fir_l, mix, idlog, ctxb, entA);

  // 7) output projection + entropy scalar
  gemm_mfma<0,0,1><<<dim3(8, 32), 256, 0, stream>>>(ctxb, wprojT, b_proj, out,
      BN_, 1024, 1024, 1024, entA, out + 4194304);
}